// Round 13
// baseline (261.681 us; speedup 1.0000x reference)
//
#include <hip/hip_runtime.h>
#include <hip/hip_bf16.h>

typedef __bf16 bf16_t;
typedef __bf16 bf16x8 __attribute__((ext_vector_type(8)));
typedef __bf16 bf16x4 __attribute__((ext_vector_type(4)));
typedef float f32x4 __attribute__((ext_vector_type(4)));
typedef float f32x16 __attribute__((ext_vector_type(16)));

// 1/sqrt(128) * log2(e)  (folded into Q so that P = exp2(S))
#define SCALE_Q2 0.12752518895325724f

__device__ __forceinline__ void gload_lds16(const void* g, void* l) {
  __builtin_amdgcn_global_load_lds(
      (const __attribute__((address_space(1))) void*)g,
      (__attribute__((address_space(3))) void*)l, 16, 0, 0);
}

// ---------------- fp32 -> bf16 convert ----------------
__global__ __launch_bounds__(256) void cvt_f32_bf16(
    const float* __restrict__ src, bf16_t* __restrict__ dst, int n4) {
  int i = blockIdx.x * 256 + threadIdx.x;
  const int stride = gridDim.x * 256;
  for (; i < n4; i += stride) {
    f32x4 v = *reinterpret_cast<const f32x4*>(src + (size_t)i * 4);
    bf16x4 r;
    r[0] = (bf16_t)v[0]; r[1] = (bf16_t)v[1];
    r[2] = (bf16_t)v[2]; r[3] = (bf16_t)v[3];
    *reinterpret_cast<bf16x4*>(dst + (size_t)i * 4) = r;
  }
}

// fused wq|wk|wv -> wqkv convert (dst contiguous, 3 sources)
__global__ __launch_bounds__(256) void cvt_qkvw(
    const float* __restrict__ wq, const float* __restrict__ wk,
    const float* __restrict__ wv, bf16_t* __restrict__ dst) {
  const int i = blockIdx.x * 256 + threadIdx.x;
  const int e = i * 4;
  const float* src;
  if (e < 4194304) src = wq + e;
  else if (e < 5242880) src = wk + (e - 4194304);
  else src = wv + (e - 5242880);
  f32x4 v = *reinterpret_cast<const f32x4*>(src);
  bf16x4 r;
  r[0] = (bf16_t)v[0]; r[1] = (bf16_t)v[1];
  r[2] = (bf16_t)v[2]; r[3] = (bf16_t)v[3];
  *reinterpret_cast<bf16x4*>(dst + e) = r;
}

// ---------------- bf16 GEMM:  C[M][N] = A[M][K] * W[N][K]^T ----------------
template <typename OutT>
__global__ __launch_bounds__(256) void gemm_bt(
    const bf16_t* __restrict__ A, const bf16_t* __restrict__ W,
    OutT* __restrict__ C, int M, int N, int K) {
  __shared__ bf16_t As[128 * 32];
  __shared__ bf16_t Ws[128 * 32];
  const int tid = threadIdx.x;
  const int lane = tid & 63;
  const int wid = tid >> 6;
  const int wr = wid >> 1, wc = wid & 1;
  const int l15 = lane & 15, lg = lane >> 4;
  const int r0 = blockIdx.y * 128;
  const int c0 = blockIdx.x * 128;

  f32x4 acc[4][4];
#pragma unroll
  for (int mi = 0; mi < 4; ++mi)
#pragma unroll
    for (int ni = 0; ni < 4; ++ni)
#pragma unroll
      for (int j = 0; j < 4; ++j) acc[mi][ni][j] = 0.f;

  for (int k0 = 0; k0 < K; k0 += 32) {
#pragma unroll
    for (int s = 0; s < 2; ++s) {
      const int chunk = wid * 2 + s;
      const int eoff = (chunk * 64 + lane) * 8;
      const int r = eoff >> 5, c = eoff & 31;
      gload_lds16(A + (size_t)(r0 + r) * K + k0 + c, (char*)As + chunk * 1024);
      gload_lds16(W + (size_t)(c0 + r) * K + k0 + c, (char*)Ws + chunk * 1024);
    }
    __syncthreads();
    bf16x8 af[4], wf[4];
#pragma unroll
    for (int mi = 0; mi < 4; ++mi)
      af[mi] = *reinterpret_cast<const bf16x8*>(
          &As[(wr * 64 + mi * 16 + l15) * 32 + lg * 8]);
#pragma unroll
    for (int ni = 0; ni < 4; ++ni)
      wf[ni] = *reinterpret_cast<const bf16x8*>(
          &Ws[(wc * 64 + ni * 16 + l15) * 32 + lg * 8]);
#pragma unroll
    for (int mi = 0; mi < 4; ++mi)
#pragma unroll
      for (int ni = 0; ni < 4; ++ni)
        acc[mi][ni] = __builtin_amdgcn_mfma_f32_16x16x32_bf16(
            af[mi], wf[ni], acc[mi][ni], 0, 0, 0);
    __syncthreads();
  }

#pragma unroll
  for (int mi = 0; mi < 4; ++mi)
#pragma unroll
    for (int ni = 0; ni < 4; ++ni)
#pragma unroll
      for (int j = 0; j < 4; ++j) {
        const int row = r0 + wr * 64 + mi * 16 + lg * 4 + j;
        const int col = c0 + wc * 64 + ni * 16 + l15;
        const float v = acc[mi][ni][j];
        if constexpr (__is_same(OutT, float))
          C[(size_t)row * N + col] = v;
        else
          C[(size_t)row * N + col] = (bf16_t)v;
      }
}

// ---------------- RoPE: qkv[4096][3072] -> Qr, Kr (coalesced only) --------
__global__ __launch_bounds__(256) void rope_layout(
    const bf16_t* __restrict__ qkv, const float* __restrict__ fc,
    const float* __restrict__ fs, bf16_t* __restrict__ Qr,
    bf16_t* __restrict__ Kr) {
  const int n = blockIdx.x;
  const int b = n >> 11, t = n & 2047;
  const int tid = threadIdx.x;
  const bf16_t* row = qkv + (size_t)n * 3072;

#pragma unroll
  for (int i = 0; i < 4; ++i) {
    const int p = i * 256 + tid;
    const int h = p >> 6, j = p & 63;
    const float t0 = (float)row[h * 128 + 2 * j];
    const float t1 = (float)row[h * 128 + 2 * j + 1];
    const float c = fc[t * 64 + j], s = fs[t * 64 + j];
    const size_t dst = ((size_t)(b * 16 + h) * 2048 + t) * 128 + 2 * j;
    Qr[dst] = (bf16_t)((t0 * c - t1 * s) * SCALE_Q2);
    Qr[dst + 1] = (bf16_t)((t0 * s + t1 * c) * SCALE_Q2);
  }
  {
    const int kvh = tid >> 6, j = tid & 63;
    const float t0 = (float)row[2048 + kvh * 128 + 2 * j];
    const float t1 = (float)row[2048 + kvh * 128 + 2 * j + 1];
    const float c = fc[t * 64 + j], s = fs[t * 64 + j];
    const size_t dst = ((size_t)(b * 4 + kvh) * 2048 + t) * 128 + 2 * j;
    Kr[dst] = (bf16_t)(t0 * c - t1 * s);
    Kr[dst + 1] = (bf16_t)(t0 * s + t1 * c);
  }
}

// ---------------- V transpose: qkv -> Vt[B*4][128][2048], LDS-tiled --------
// Token columns permuted within 16-groups (swap bits 2<->3 of t&15).
__global__ __launch_bounds__(256) void v_trans(
    const bf16_t* __restrict__ qkv, bf16_t* __restrict__ Vt) {
  __shared__ bf16_t L[64][68];
  const int bid = blockIdx.x;
  const int tt = bid & 31;
  const int dt2 = (bid >> 5) & 1;
  const int bk = bid >> 6;
  const int b = bk >> 2, kvh = bk & 3;
  const int t0 = tt * 64, d0 = dt2 * 64;
  const int r = threadIdx.x >> 4;
  const int c4 = (threadIdx.x & 15) * 4;

#pragma unroll
  for (int it = 0; it < 4; ++it) {
    const int tl = r + it * 16;
    const int tp = (tl & ~15) |
                   ((tl & 3) | ((tl & 4) << 1) | ((tl & 8) >> 1));
    const bf16_t* src = qkv + (size_t)(b * 2048 + t0 + tl) * 3072 + 2560 +
                        kvh * 128 + d0 + c4;
    *reinterpret_cast<bf16x4*>(&L[tp][c4]) =
        *reinterpret_cast<const bf16x4*>(src);
  }
  __syncthreads();
#pragma unroll
  for (int it = 0; it < 4; ++it) {
    const int dr = r + it * 16;
    bf16x4 v;
#pragma unroll
    for (int j = 0; j < 4; ++j) v[j] = L[c4 + j][dr];
    *reinterpret_cast<bf16x4*>(Vt + ((size_t)bk * 128 + d0 + dr) * 2048 +
                               t0 + c4) = v;
  }
}

// ---------------- causal GQA flash attention (32x32 MFMA, swapped QK) ------
// KV-SPLIT, 2-tile window, 4-buffer ring. 512 threads = 8 waves; wave =
// (qw, half): waves (qw,0) and (qw,1) share the same 32 q-rows and split the
// KV tiles by parity (half0 = even 64-kv tiles, half1 = odd). Window j stages
// tiles 2j+2, 2j+3 then BOTH halves compute concurrently from different
// buffers -> all 16 waves/CU active (2x round-10's 8). One barrier/window.
// Static softmax => additive merge (O,lsum) via LDS at the end.
// LDS 4x16KB + 1KB = 66KB -> 2 blocks/CU. launch_bounds (512,2): arg=2 is
// the allocator-safe setting (arg=4 collapses to 64 VGPR + spill, r9/r11).
__global__ __launch_bounds__(512, 2) void attn_fwd(
    const bf16_t* __restrict__ Qr, const bf16_t* __restrict__ Kr,
    const bf16_t* __restrict__ Vt, bf16_t* __restrict__ Oout) {
  __shared__ __align__(16) bf16_t Klds[4][64 * 128];
  __shared__ float LS[4][64];
  const int tid = threadIdx.x;
  const int lane = tid & 63, W = tid >> 6;
  const int qw = W & 3, half = W >> 2;
  const int l31 = lane & 31, hi = lane >> 5;
  const int sidx = blockIdx.x >> 5;
  const int hb = blockIdx.x & 31;
  const int h = hb & 15, b = hb >> 4;
  const int kvh = h >> 2;
  const int st = (sidx < 8) ? (15 - sidx) : (sidx - 8);  // pair (15-s, s)

  const bf16_t* Kbase = Kr + ((size_t)(b * 4 + kvh) * 2048) * 128;
  const bf16_t* Vbase = Vt + ((size_t)(b * 4 + kvh) * 128) * 2048;

  const int qbw = st * 128 + qw * 32;
  const bf16_t* Qbase = Qr + ((size_t)(b * 16 + h) * 2048 + qbw + l31) * 128;

  auto STAGE = [&](bf16_t* dst, int t) {
    const int k0s = t * 64;
#pragma unroll
    for (int i = 0; i < 2; ++i) {
      const int c = i * 512 + tid;           // 16B-chunk id [0,1024)
      const int row = c >> 4;
      const int col = c & 15;
      const int scol = col ^ (row & 15);     // pre-swizzled source col
      gload_lds16(Kbase + (size_t)(k0s + row) * 128 + scol * 8, dst + c * 8);
    }
  };

  // prologue: stage window 0 (tiles 0,1)
  STAGE(&Klds[0][0], 0);
  STAGE(&Klds[1][0], 1);

  bf16x8 qf[8];
#pragma unroll
  for (int dt = 0; dt < 8; ++dt)
    qf[dt] = *reinterpret_cast<const bf16x8*>(Qbase + dt * 16 + hi * 8);

  f32x16 o[4];
#pragma unroll
  for (int d = 0; d < 4; ++d)
#pragma unroll
    for (int r = 0; r < 16; ++r) o[d][r] = 0.f;
  float lsum = 0.f;

  const int nw = st + 1;                     // windows of 2x64-kv tiles
  for (int j = 0; j < nw; ++j) {
    __syncthreads();  // window-j tiles landed; window-(j-1) compute done
    if (j + 1 < nw) {
      STAGE(&Klds[(2 * j + 2) & 3][0], 2 * j + 2);
      STAGE(&Klds[(2 * j + 3) & 3][0], 2 * j + 3);
    }
    const int t = 2 * j + half;              // this half's tile
    const int k0 = t * 64;
    if (k0 <= qbw) {
      const bool do1 = (k0 + 32 <= qbw);
      const char* KB = (const char*)&Klds[t & 3][0];

      auto QK = [&](f32x16& sv, int qi) __attribute__((always_inline)) {
#pragma unroll
        for (int r = 0; r < 16; ++r) sv[r] = 0.f;
#pragma unroll
        for (int dt = 0; dt < 8; ++dt) {
          const int boff = (qi * 32 + l31) * 256 +
                           ((dt * 32 + hi * 16) ^ ((l31 & 15) << 4));
          bf16x8 ka = *reinterpret_cast<const bf16x8*>(KB + boff);
          sv = __builtin_amdgcn_mfma_f32_32x32x16_bf16(ka, qf[dt], sv, 0, 0, 0);
        }
      };
      auto VLOADQ = [&](bf16x8 buf[4], int qi, int kc)
          __attribute__((always_inline)) {
#pragma unroll
        for (int dtile = 0; dtile < 4; ++dtile)
          buf[dtile] = *reinterpret_cast<const bf16x8*>(
              Vbase + (size_t)(dtile * 32 + l31) * 2048 + k0 + qi * 32 +
              kc * 16 + hi * 8);
      };
      auto SMPV = [&](const f32x16& sv, bool diag, bf16x8 va0[4],
                      bf16x8 va1[4]) __attribute__((always_inline)) {
        float p[16];
#pragma unroll
        for (int r = 0; r < 16; ++r) {
          float e = exp2f(sv[r]);
          if (diag) {
            const int crow = (r & 3) + 8 * (r >> 2) + 4 * hi;
            if (crow > l31) e = 0.f;
          }
          p[r] = e;
        }
        const float t0 = (p[0] + p[1]) + (p[2] + p[3]);
        const float t1 = (p[4] + p[5]) + (p[6] + p[7]);
        const float t2 = (p[8] + p[9]) + (p[10] + p[11]);
        const float t3 = (p[12] + p[13]) + (p[14] + p[15]);
        lsum += (t0 + t1) + (t2 + t3);
#pragma unroll
        for (int kc = 0; kc < 2; ++kc) {
          unsigned int u0, u1, u2, u3;
          asm("v_cvt_pk_bf16_f32 %0, %1, %2" : "=v"(u0)
              : "v"(p[8 * kc + 0]), "v"(p[8 * kc + 1]));
          asm("v_cvt_pk_bf16_f32 %0, %1, %2" : "=v"(u1)
              : "v"(p[8 * kc + 2]), "v"(p[8 * kc + 3]));
          asm("v_cvt_pk_bf16_f32 %0, %1, %2" : "=v"(u2)
              : "v"(p[8 * kc + 4]), "v"(p[8 * kc + 5]));
          asm("v_cvt_pk_bf16_f32 %0, %1, %2" : "=v"(u3)
              : "v"(p[8 * kc + 6]), "v"(p[8 * kc + 7]));
          union { unsigned int u[4]; bf16x8 v; } pb;
          pb.u[0] = u0; pb.u[1] = u1; pb.u[2] = u2; pb.u[3] = u3;
          bf16x8* va = kc ? va1 : va0;
          __builtin_amdgcn_s_setprio(1);
#pragma unroll
          for (int dtile = 0; dtile < 4; ++dtile)
            o[dtile] = __builtin_amdgcn_mfma_f32_32x32x16_bf16(
                va[dtile], pb.v, o[dtile], 0, 0, 0);
          __builtin_amdgcn_s_setprio(0);
        }
      };

      // V prefetch for quarter 0 (lands under QK^T)
      bf16x8 vaA[4], vaB[4];
      VLOADQ(vaA, 0, 0);
      VLOADQ(vaB, 0, 1);

      f32x16 sA, sB;
      __builtin_amdgcn_s_setprio(1);
      QK(sA, 0);
      if (do1) QK(sB, 1);
      __builtin_amdgcn_s_setprio(0);

      SMPV(sA, k0 == qbw, vaA, vaB);
      if (do1) {
        VLOADQ(vaA, 1, 0);
        VLOADQ(vaB, 1, 1);
        SMPV(sB, k0 + 32 == qbw, vaA, vaB);
      }
    }
  }

  // ---- merge halves (static softmax => pure addition) ----
  __syncthreads();                        // all compute done; Klds reusable
  float* F = (float*)&Klds[0][0];         // idx-major: conflict-free
  if (half == 1) {
#pragma unroll
    for (int dtile = 0; dtile < 4; ++dtile)
#pragma unroll
      for (int r = 0; r < 16; ++r)
        F[(dtile * 16 + r) * 256 + qw * 64 + lane] = o[dtile][r];
    LS[qw][lane] = lsum;
  }
  __syncthreads();
  if (half == 0) {
    lsum += LS[qw][lane];
#pragma unroll
    for (int dtile = 0; dtile < 4; ++dtile)
#pragma unroll
      for (int r = 0; r < 16; ++r)
        o[dtile][r] += F[(dtile * 16 + r) * 256 + qw * 64 + lane];

    const float ltot = lsum + __shfl_xor(lsum, 32);
    const float inv = 1.f / ltot;
    bf16_t* Obase = Oout + ((size_t)b * 2048 + qbw + l31) * 2048 + h * 128;
#pragma unroll
    for (int dtile = 0; dtile < 4; ++dtile)
#pragma unroll
      for (int g = 0; g < 4; ++g) {
        bf16x4 stv;
#pragma unroll
        for (int j2 = 0; j2 < 4; ++j2)
          stv[j2] = (bf16_t)(o[dtile][g * 4 + j2] * inv);
        *reinterpret_cast<bf16x4*>(Obase + dtile * 32 + 8 * g + 4 * hi) = stv;
      }
  }
}

// ---------------- host launch ----------------
extern "C" void kernel_launch(void* const* d_in, const int* in_sizes, int n_in,
                              void* d_out, int out_size, void* d_ws,
                              size_t ws_size, hipStream_t stream) {
  const float* x  = (const float*)d_in[0];
  const float* wq = (const float*)d_in[1];
  const float* wk = (const float*)d_in[2];
  const float* wv = (const float*)d_in[3];
  const float* wo = (const float*)d_in[4];
  const float* fc = (const float*)d_in[5];
  const float* fs = (const float*)d_in[6];
  float* out = (float*)d_out;

  char* ws = (char*)d_ws;
  bf16_t* xb      = (bf16_t*)(ws + 0);
  bf16_t* wqkv    = (bf16_t*)(ws + 16777216);
  bf16_t* wo_b    = (bf16_t*)(ws + 29360128);
  bf16_t* qkv     = (bf16_t*)(ws + 37748736);
  bf16_t* Qr      = (bf16_t*)(ws + 62914560);
  bf16_t* Kr      = (bf16_t*)(ws + 79691776);
  bf16_t* Vt      = (bf16_t*)(ws + 83886080);
  bf16_t* attn_o  = xb;

  const int M = 4096;

  cvt_f32_bf16<<<2048, 256, 0, stream>>>(x, xb, 2097152);
  cvt_qkvw<<<6144, 256, 0, stream>>>(wq, wk, wv, wqkv);
  cvt_f32_bf16<<<1024, 256, 0, stream>>>(wo, wo_b, 1048576);

  gemm_bt<bf16_t><<<dim3(3072 / 128, M / 128), 256, 0, stream>>>(
      xb, wqkv, qkv, M, 3072, 2048);

  rope_layout<<<4096, 256, 0, stream>>>(qkv, fc, fs, Qr, Kr);
  v_trans<<<512, 256, 0, stream>>>(qkv, Vt);

  attn_fwd<<<512, 512, 0, stream>>>(Qr, Kr, Vt, attn_o);

  gemm_bt<float><<<dim3(2048 / 128, M / 128), 256, 0, stream>>>(
      attn_o, wo_b, out, M, 2048, 2048);
}

// Round 14
// 240.229 us; speedup vs baseline: 1.0893x; 1.0893x over previous
//
#include <hip/hip_runtime.h>
#include <hip/hip_bf16.h>

typedef __bf16 bf16_t;
typedef __bf16 bf16x8 __attribute__((ext_vector_type(8)));
typedef __bf16 bf16x4 __attribute__((ext_vector_type(4)));
typedef float f32x4 __attribute__((ext_vector_type(4)));
typedef float f32x16 __attribute__((ext_vector_type(16)));

// 1/sqrt(128) * log2(e)  (folded into Q so that P = exp2(S))
#define SCALE_Q2 0.12752518895325724f

__device__ __forceinline__ void gload_lds16(const void* g, void* l) {
  __builtin_amdgcn_global_load_lds(
      (const __attribute__((address_space(1))) void*)g,
      (__attribute__((address_space(3))) void*)l, 16, 0, 0);
}

// ---------------- fused fp32 -> bf16 converts (x | wq|wk|wv | wo) ----------
// One grid-stride kernel over all 18,874,368 elements (4,718,592 groups of 4).
__global__ __launch_bounds__(256) void cvt_all(
    const float* __restrict__ x, const float* __restrict__ wq,
    const float* __restrict__ wk, const float* __restrict__ wv,
    const float* __restrict__ wo, bf16_t* __restrict__ xb,
    bf16_t* __restrict__ wqkv, bf16_t* __restrict__ wo_b) {
  int i = blockIdx.x * 256 + threadIdx.x;
  const int stride = gridDim.x * 256;
  for (; i < 4718592; i += stride) {
    const int e = i * 4;
    const float* src;
    bf16_t* dst;
    if (e < 8388608) {
      src = x + e;              dst = xb + e;
    } else if (e < 12582912) {
      src = wq + (e - 8388608); dst = wqkv + (e - 8388608);
    } else if (e < 13631488) {
      src = wk + (e - 12582912); dst = wqkv + (e - 8388608);
    } else if (e < 14680064) {
      src = wv + (e - 13631488); dst = wqkv + (e - 8388608);
    } else {
      src = wo + (e - 14680064); dst = wo_b + (e - 14680064);
    }
    f32x4 v = *reinterpret_cast<const f32x4*>(src);
    bf16x4 r;
    r[0] = (bf16_t)v[0]; r[1] = (bf16_t)v[1];
    r[2] = (bf16_t)v[2]; r[3] = (bf16_t)v[3];
    *reinterpret_cast<bf16x4*>(dst) = r;
  }
}

// ---------------- bf16 GEMM:  C[M][N] = A[M][K] * W[N][K]^T ----------------
template <typename OutT>
__global__ __launch_bounds__(256) void gemm_bt(
    const bf16_t* __restrict__ A, const bf16_t* __restrict__ W,
    OutT* __restrict__ C, int M, int N, int K) {
  __shared__ bf16_t As[128 * 32];
  __shared__ bf16_t Ws[128 * 32];
  const int tid = threadIdx.x;
  const int lane = tid & 63;
  const int wid = tid >> 6;
  const int wr = wid >> 1, wc = wid & 1;
  const int l15 = lane & 15, lg = lane >> 4;
  const int r0 = blockIdx.y * 128;
  const int c0 = blockIdx.x * 128;

  f32x4 acc[4][4];
#pragma unroll
  for (int mi = 0; mi < 4; ++mi)
#pragma unroll
    for (int ni = 0; ni < 4; ++ni)
#pragma unroll
      for (int j = 0; j < 4; ++j) acc[mi][ni][j] = 0.f;

  for (int k0 = 0; k0 < K; k0 += 32) {
#pragma unroll
    for (int s = 0; s < 2; ++s) {
      const int chunk = wid * 2 + s;
      const int eoff = (chunk * 64 + lane) * 8;
      const int r = eoff >> 5, c = eoff & 31;
      gload_lds16(A + (size_t)(r0 + r) * K + k0 + c, (char*)As + chunk * 1024);
      gload_lds16(W + (size_t)(c0 + r) * K + k0 + c, (char*)Ws + chunk * 1024);
    }
    __syncthreads();
    bf16x8 af[4], wf[4];
#pragma unroll
    for (int mi = 0; mi < 4; ++mi)
      af[mi] = *reinterpret_cast<const bf16x8*>(
          &As[(wr * 64 + mi * 16 + l15) * 32 + lg * 8]);
#pragma unroll
    for (int ni = 0; ni < 4; ++ni)
      wf[ni] = *reinterpret_cast<const bf16x8*>(
          &Ws[(wc * 64 + ni * 16 + l15) * 32 + lg * 8]);
#pragma unroll
    for (int mi = 0; mi < 4; ++mi)
#pragma unroll
      for (int ni = 0; ni < 4; ++ni)
        acc[mi][ni] = __builtin_amdgcn_mfma_f32_16x16x32_bf16(
            af[mi], wf[ni], acc[mi][ni], 0, 0, 0);
    __syncthreads();
  }

#pragma unroll
  for (int mi = 0; mi < 4; ++mi)
#pragma unroll
    for (int ni = 0; ni < 4; ++ni)
#pragma unroll
      for (int j = 0; j < 4; ++j) {
        const int row = r0 + wr * 64 + mi * 16 + lg * 4 + j;
        const int col = c0 + wc * 64 + ni * 16 + l15;
        const float v = acc[mi][ni][j];
        if constexpr (__is_same(OutT, float))
          C[(size_t)row * N + col] = v;
        else
          C[(size_t)row * N + col] = (bf16_t)v;
      }
}

// ---------------- RoPE: qkv[4096][3072] -> Qr, Kr (coalesced only) --------
__global__ __launch_bounds__(256) void rope_layout(
    const bf16_t* __restrict__ qkv, const float* __restrict__ fc,
    const float* __restrict__ fs, bf16_t* __restrict__ Qr,
    bf16_t* __restrict__ Kr) {
  const int n = blockIdx.x;
  const int b = n >> 11, t = n & 2047;
  const int tid = threadIdx.x;
  const bf16_t* row = qkv + (size_t)n * 3072;

#pragma unroll
  for (int i = 0; i < 4; ++i) {
    const int p = i * 256 + tid;
    const int h = p >> 6, j = p & 63;
    const float t0 = (float)row[h * 128 + 2 * j];
    const float t1 = (float)row[h * 128 + 2 * j + 1];
    const float c = fc[t * 64 + j], s = fs[t * 64 + j];
    const size_t dst = ((size_t)(b * 16 + h) * 2048 + t) * 128 + 2 * j;
    Qr[dst] = (bf16_t)((t0 * c - t1 * s) * SCALE_Q2);
    Qr[dst + 1] = (bf16_t)((t0 * s + t1 * c) * SCALE_Q2);
  }
  {
    const int kvh = tid >> 6, j = tid & 63;
    const float t0 = (float)row[2048 + kvh * 128 + 2 * j];
    const float t1 = (float)row[2048 + kvh * 128 + 2 * j + 1];
    const float c = fc[t * 64 + j], s = fs[t * 64 + j];
    const size_t dst = ((size_t)(b * 4 + kvh) * 2048 + t) * 128 + 2 * j;
    Kr[dst] = (bf16_t)(t0 * c - t1 * s);
    Kr[dst + 1] = (bf16_t)(t0 * s + t1 * c);
  }
}

// ---------------- V transpose: qkv -> Vt[B*4][128][2048], LDS-tiled --------
// Token columns permuted within 16-groups (swap bits 2<->3 of t&15).
__global__ __launch_bounds__(256) void v_trans(
    const bf16_t* __restrict__ qkv, bf16_t* __restrict__ Vt) {
  __shared__ bf16_t L[64][68];
  const int bid = blockIdx.x;
  const int tt = bid & 31;
  const int dt2 = (bid >> 5) & 1;
  const int bk = bid >> 6;
  const int b = bk >> 2, kvh = bk & 3;
  const int t0 = tt * 64, d0 = dt2 * 64;
  const int r = threadIdx.x >> 4;
  const int c4 = (threadIdx.x & 15) * 4;

#pragma unroll
  for (int it = 0; it < 4; ++it) {
    const int tl = r + it * 16;
    const int tp = (tl & ~15) |
                   ((tl & 3) | ((tl & 4) << 1) | ((tl & 8) >> 1));
    const bf16_t* src = qkv + (size_t)(b * 2048 + t0 + tl) * 3072 + 2560 +
                        kvh * 128 + d0 + c4;
    *reinterpret_cast<bf16x4*>(&L[tp][c4]) =
        *reinterpret_cast<const bf16x4*>(src);
  }
  __syncthreads();
#pragma unroll
  for (int it = 0; it < 4; ++it) {
    const int dr = r + it * 16;
    bf16x4 v;
#pragma unroll
    for (int j = 0; j < 4; ++j) v[j] = L[c4 + j][dr];
    *reinterpret_cast<bf16x4*>(Vt + ((size_t)bk * 128 + d0 + dr) * 2048 +
                               t0 + c4) = v;
  }
}

// ---------------- causal GQA flash attention (32x32 MFMA, swapped QK) ------
// Round-10 structure (best known): 4 waves x 32q, KVBLK=128, K dbuf 64KB,
// kf-pair QK^T + V ping-pong register prefetch. NEW: each tile's kf=0 V
// prefetch is issued BEFORE the barrier (loads complete during the barrier's
// vmcnt drain instead of stalling the first PV).
#define VLOAD(buf, kf, kc)                                               \
  {                                                                      \
    _Pragma("unroll") for (int dtile_ = 0; dtile_ < 4; ++dtile_)         \
        buf[dtile_] = *reinterpret_cast<const bf16x8*>(                  \
            Vbase + (size_t)(dtile_ * 32 + l31) * 2048 + k0 + (kf) * 32 +\
            (kc) * 16 + hi * 8);                                         \
  }

__global__ __launch_bounds__(256, 2) void attn_fwd(
    const bf16_t* __restrict__ Qr, const bf16_t* __restrict__ Kr,
    const bf16_t* __restrict__ Vt, bf16_t* __restrict__ Oout) {
  __shared__ __align__(16) bf16_t Klds[2][128 * 128];
  const int tid = threadIdx.x;
  const int lane = tid & 63, w = tid >> 6;
  const int l31 = lane & 31, hi = lane >> 5;
  const int sidx = blockIdx.x >> 5;
  const int hb = blockIdx.x & 31;
  const int h = hb & 15, b = hb >> 4;
  const int kvh = h >> 2;
  const int st = (sidx < 8) ? (15 - sidx) : (sidx - 8);

  const bf16_t* Kbase = Kr + ((size_t)(b * 4 + kvh) * 2048) * 128;
  const bf16_t* Vbase = Vt + ((size_t)(b * 4 + kvh) * 128) * 2048;

  const int qbw = st * 128 + w * 32;
  const bf16_t* Qbase = Qr + ((size_t)(b * 16 + h) * 2048 + qbw + l31) * 128;

  auto STAGE = [&](bf16_t* dst, int kt) {
    const int k0s = kt * 128;
#pragma unroll
    for (int i = 0; i < 8; ++i) {
      const int c = i * 256 + tid;
      const int row = c >> 4;
      const int col = c & 15;
      const int scol = col ^ (row & 15);
      gload_lds16(Kbase + (size_t)(k0s + row) * 128 + scol * 8, dst + c * 8);
    }
  };

  STAGE(&Klds[0][0], 0);

  bf16x8 qf[8];
#pragma unroll
  for (int dt = 0; dt < 8; ++dt)
    qf[dt] = *reinterpret_cast<const bf16x8*>(Qbase + dt * 16 + hi * 8);

  f32x16 o[4];
#pragma unroll
  for (int d = 0; d < 4; ++d)
#pragma unroll
    for (int r = 0; r < 16; ++r) o[d][r] = 0.f;
  float lsum = 0.f;

  const int nt = st + 1;
  int cur = 0;
  for (int kt = 0; kt < nt; ++kt) {
    const int k0 = kt * 128;
    const bool last = (kt == nt - 1);
    const int kfmax = last ? w : 3;

    // V prefetch for kf=0, issued BEFORE the barrier (lands during the
    // barrier's vmcnt drain; kf=0 is always computed by every wave).
    bf16x8 vaA[4], vaB[4];
    VLOAD(vaA, 0, 0);
    VLOAD(vaB, 0, 1);

    __syncthreads();  // prev STAGE drained; all readers of other buf done
    if (kt + 1 < nt) STAGE(&Klds[cur ^ 1][0], kt + 1);

    const char* KB = (const char*)&Klds[cur][0];

#pragma unroll
    for (int kp = 0; kp < 2; ++kp) {
      // ---- QK^T for kf pair (2kp, 2kp+1): two independent MFMA chains ----
      f32x16 sA, sB;
      __builtin_amdgcn_s_setprio(1);
      if (2 * kp <= kfmax) {
#pragma unroll
        for (int r = 0; r < 16; ++r) sA[r] = 0.f;
#pragma unroll
        for (int dt = 0; dt < 8; ++dt) {
          const int boff = ((2 * kp) * 32 + l31) * 256 +
                           ((dt * 32 + hi * 16) ^ ((l31 & 15) << 4));
          bf16x8 ka = *reinterpret_cast<const bf16x8*>(KB + boff);
          sA = __builtin_amdgcn_mfma_f32_32x32x16_bf16(ka, qf[dt], sA, 0, 0, 0);
        }
      }
      if (2 * kp + 1 <= kfmax) {
#pragma unroll
        for (int r = 0; r < 16; ++r) sB[r] = 0.f;
#pragma unroll
        for (int dt = 0; dt < 8; ++dt) {
          const int boff = ((2 * kp + 1) * 32 + l31) * 256 +
                           ((dt * 32 + hi * 16) ^ ((l31 & 15) << 4));
          bf16x8 ka = *reinterpret_cast<const bf16x8*>(KB + boff);
          sB = __builtin_amdgcn_mfma_f32_32x32x16_bf16(ka, qf[dt], sB, 0, 0, 0);
        }
      }
      __builtin_amdgcn_s_setprio(0);

      // ---- softmax + PV per kf in the pair ----
#pragma unroll
      for (int ki = 0; ki < 2; ++ki) {
        const int kf = 2 * kp + ki;
        if (kf <= kfmax) {
          const bool diag = last && (kf == w);
          float p[16];
#pragma unroll
          for (int r = 0; r < 16; ++r) {
            float e = exp2f(ki ? sB[r] : sA[r]);
            if (diag) {
              const int crow = (r & 3) + 8 * (r >> 2) + 4 * hi;
              if (crow > l31) e = 0.f;
            }
            p[r] = e;
          }
          const float t0 = (p[0] + p[1]) + (p[2] + p[3]);
          const float t1 = (p[4] + p[5]) + (p[6] + p[7]);
          const float t2 = (p[8] + p[9]) + (p[10] + p[11]);
          const float t3 = (p[12] + p[13]) + (p[14] + p[15]);
          lsum += (t0 + t1) + (t2 + t3);

          // kc0: consume vaA, then reload it for kf+1
          {
            unsigned int u0, u1, u2, u3;
            asm("v_cvt_pk_bf16_f32 %0, %1, %2" : "=v"(u0)
                : "v"(p[0]), "v"(p[1]));
            asm("v_cvt_pk_bf16_f32 %0, %1, %2" : "=v"(u1)
                : "v"(p[2]), "v"(p[3]));
            asm("v_cvt_pk_bf16_f32 %0, %1, %2" : "=v"(u2)
                : "v"(p[4]), "v"(p[5]));
            asm("v_cvt_pk_bf16_f32 %0, %1, %2" : "=v"(u3)
                : "v"(p[6]), "v"(p[7]));
            union { unsigned int u[4]; bf16x8 v; } pb;
            pb.u[0] = u0; pb.u[1] = u1; pb.u[2] = u2; pb.u[3] = u3;
            __builtin_amdgcn_s_setprio(1);
#pragma unroll
            for (int dtile = 0; dtile < 4; ++dtile)
              o[dtile] = __builtin_amdgcn_mfma_f32_32x32x16_bf16(
                  vaA[dtile], pb.v, o[dtile], 0, 0, 0);
            __builtin_amdgcn_s_setprio(0);
          }
          if (kf < kfmax) VLOAD(vaA, kf + 1, 0);

          // kc1: consume vaB, then reload it for kf+1
          {
            unsigned int u0, u1, u2, u3;
            asm("v_cvt_pk_bf16_f32 %0, %1, %2" : "=v"(u0)
                : "v"(p[8]), "v"(p[9]));
            asm("v_cvt_pk_bf16_f32 %0, %1, %2" : "=v"(u1)
                : "v"(p[10]), "v"(p[11]));
            asm("v_cvt_pk_bf16_f32 %0, %1, %2" : "=v"(u2)
                : "v"(p[12]), "v"(p[13]));
            asm("v_cvt_pk_bf16_f32 %0, %1, %2" : "=v"(u3)
                : "v"(p[14]), "v"(p[15]));
            union { unsigned int u[4]; bf16x8 v; } pb;
            pb.u[0] = u0; pb.u[1] = u1; pb.u[2] = u2; pb.u[3] = u3;
            __builtin_amdgcn_s_setprio(1);
#pragma unroll
            for (int dtile = 0; dtile < 4; ++dtile)
              o[dtile] = __builtin_amdgcn_mfma_f32_32x32x16_bf16(
                  vaB[dtile], pb.v, o[dtile], 0, 0, 0);
            __builtin_amdgcn_s_setprio(0);
          }
          if (kf < kfmax) VLOAD(vaB, kf + 1, 1);
        }
      }
    }
    cur ^= 1;
  }

  // ---- epilogue: normalize + store O^T (col=q, row=d) ----
  const float ltot = lsum + __shfl_xor(lsum, 32);
  const float inv = 1.f / ltot;
  bf16_t* Obase = Oout + ((size_t)b * 2048 + qbw + l31) * 2048 + h * 128;
#pragma unroll
  for (int dtile = 0; dtile < 4; ++dtile)
#pragma unroll
    for (int g = 0; g < 4; ++g) {
      bf16x4 stv;
#pragma unroll
      for (int j = 0; j < 4; ++j)
        stv[j] = (bf16_t)(o[dtile][g * 4 + j] * inv);
      *reinterpret_cast<bf16x4*>(Obase + dtile * 32 + 8 * g + 4 * hi) = stv;
    }
}

// ---------------- host launch ----------------
extern "C" void kernel_launch(void* const* d_in, const int* in_sizes, int n_in,
                              void* d_out, int out_size, void* d_ws,
                              size_t ws_size, hipStream_t stream) {
  const float* x  = (const float*)d_in[0];
  const float* wq = (const float*)d_in[1];
  const float* wk = (const float*)d_in[2];
  const float* wv = (const float*)d_in[3];
  const float* wo = (const float*)d_in[4];
  const float* fc = (const float*)d_in[5];
  const float* fs = (const float*)d_in[6];
  float* out = (float*)d_out;

  char* ws = (char*)d_ws;
  bf16_t* xb      = (bf16_t*)(ws + 0);
  bf16_t* wqkv    = (bf16_t*)(ws + 16777216);
  bf16_t* wo_b    = (bf16_t*)(ws + 29360128);
  bf16_t* qkv     = (bf16_t*)(ws + 37748736);
  bf16_t* Qr      = (bf16_t*)(ws + 62914560);
  bf16_t* Kr      = (bf16_t*)(ws + 79691776);
  bf16_t* Vt      = (bf16_t*)(ws + 83886080);
  bf16_t* attn_o  = xb;

  const int M = 4096;

  cvt_all<<<2048, 256, 0, stream>>>(x, wq, wk, wv, wo, xb, wqkv, wo_b);

  gemm_bt<bf16_t><<<dim3(3072 / 128, M / 128), 256, 0, stream>>>(
      xb, wqkv, qkv, M, 3072, 2048);

  rope_layout<<<4096, 256, 0, stream>>>(qkv, fc, fs, Qr, Kr);
  v_trans<<<512, 256, 0, stream>>>(qkv, Vt);

  attn_fwd<<<512, 256, 0, stream>>>(Qr, Kr, Vt, attn_o);

  gemm_bt<float><<<dim3(2048 / 128, M / 128), 256, 0, stream>>>(
      attn_o, wo_b, out, M, 2048, 2048);
}

// Round 15
// 213.051 us; speedup vs baseline: 1.2283x; 1.1276x over previous
//
#include <hip/hip_runtime.h>
#include <hip/hip_bf16.h>

typedef __bf16 bf16_t;
typedef __bf16 bf16x8 __attribute__((ext_vector_type(8)));
typedef __bf16 bf16x4 __attribute__((ext_vector_type(4)));
typedef float f32x4 __attribute__((ext_vector_type(4)));
typedef float f32x16 __attribute__((ext_vector_type(16)));

// 1/sqrt(128) * log2(e)  (folded into Q so that P = exp2(S))
#define SCALE_Q2 0.12752518895325724f

__device__ __forceinline__ void gload_lds16(const void* g, void* l) {
  __builtin_amdgcn_global_load_lds(
      (const __attribute__((address_space(1))) void*)g,
      (__attribute__((address_space(3))) void*)l, 16, 0, 0);
}

// ---------------- fused fp32 -> bf16 converts (x | wq|wk|wv | wo) ----------
__global__ __launch_bounds__(256) void cvt_all(
    const float* __restrict__ x, const float* __restrict__ wq,
    const float* __restrict__ wk, const float* __restrict__ wv,
    const float* __restrict__ wo, bf16_t* __restrict__ xb,
    bf16_t* __restrict__ wqkv, bf16_t* __restrict__ wo_b) {
  int i = blockIdx.x * 256 + threadIdx.x;
  const int stride = gridDim.x * 256;
  for (; i < 4718592; i += stride) {
    const int e = i * 4;
    const float* src;
    bf16_t* dst;
    if (e < 8388608) {
      src = x + e;              dst = xb + e;
    } else if (e < 12582912) {
      src = wq + (e - 8388608); dst = wqkv + (e - 8388608);
    } else if (e < 13631488) {
      src = wk + (e - 12582912); dst = wqkv + (e - 8388608);
    } else if (e < 14680064) {
      src = wv + (e - 13631488); dst = wqkv + (e - 8388608);
    } else {
      src = wo + (e - 14680064); dst = wo_b + (e - 14680064);
    }
    f32x4 v = *reinterpret_cast<const f32x4*>(src);
    bf16x4 r;
    r[0] = (bf16_t)v[0]; r[1] = (bf16_t)v[1];
    r[2] = (bf16_t)v[2]; r[3] = (bf16_t)v[3];
    *reinterpret_cast<bf16x4*>(dst) = r;
  }
}

// ---------------- bf16 GEMM:  C[M][N] = A[M][K] * W[N][K]^T ----------------
// BK=64 (halved barrier count vs BK=32), single-buffered 32KB LDS.
// Row stride 128B => b128 reads need the XOR involution (16B-chunk ^ row&7):
// source pre-swizzled, read applies same XOR (rule 21; 8 lanes cover all 32
// banks once, 2-way residual = free).
template <typename OutT>
__global__ __launch_bounds__(256) void gemm_bt(
    const bf16_t* __restrict__ A, const bf16_t* __restrict__ W,
    OutT* __restrict__ C, int M, int N, int K) {
  __shared__ __align__(16) bf16_t As[128 * 64];
  __shared__ __align__(16) bf16_t Ws[128 * 64];
  const int tid = threadIdx.x;
  const int lane = tid & 63;
  const int wid = tid >> 6;
  const int wr = wid >> 1, wc = wid & 1;
  const int l15 = lane & 15, lg = lane >> 4;
  const int r0 = blockIdx.y * 128;
  const int c0 = blockIdx.x * 128;

  f32x4 acc[4][4];
#pragma unroll
  for (int mi = 0; mi < 4; ++mi)
#pragma unroll
    for (int ni = 0; ni < 4; ++ni)
#pragma unroll
      for (int j = 0; j < 4; ++j) acc[mi][ni][j] = 0.f;

  for (int k0 = 0; k0 < K; k0 += 64) {
#pragma unroll
    for (int s = 0; s < 4; ++s) {
      const int c = s * 256 + tid;            // 16B-chunk id [0,1024)
      const int row = c >> 3;
      const int scol = (c & 7) ^ (row & 7);   // pre-swizzled source chunk
      gload_lds16(A + (size_t)(r0 + row) * K + k0 + scol * 8,
                  (char*)As + c * 16);
      gload_lds16(W + (size_t)(c0 + row) * K + k0 + scol * 8,
                  (char*)Ws + c * 16);
    }
    __syncthreads();
#pragma unroll
    for (int kk = 0; kk < 2; ++kk) {
      bf16x8 af[4], wf[4];
#pragma unroll
      for (int mi = 0; mi < 4; ++mi) {
        const int r = wr * 64 + mi * 16 + l15;
        af[mi] = *reinterpret_cast<const bf16x8*>(
            (char*)As + r * 128 + ((kk * 64 + lg * 16) ^ ((r & 7) << 4)));
      }
#pragma unroll
      for (int ni = 0; ni < 4; ++ni) {
        const int r = wc * 64 + ni * 16 + l15;
        wf[ni] = *reinterpret_cast<const bf16x8*>(
            (char*)Ws + r * 128 + ((kk * 64 + lg * 16) ^ ((r & 7) << 4)));
      }
#pragma unroll
      for (int mi = 0; mi < 4; ++mi)
#pragma unroll
        for (int ni = 0; ni < 4; ++ni)
          acc[mi][ni] = __builtin_amdgcn_mfma_f32_16x16x32_bf16(
              af[mi], wf[ni], acc[mi][ni], 0, 0, 0);
    }
    __syncthreads();
  }

#pragma unroll
  for (int mi = 0; mi < 4; ++mi)
#pragma unroll
    for (int ni = 0; ni < 4; ++ni)
#pragma unroll
      for (int j = 0; j < 4; ++j) {
        const int row = r0 + wr * 64 + mi * 16 + lg * 4 + j;
        const int col = c0 + wc * 64 + ni * 16 + l15;
        const float v = acc[mi][ni][j];
        if constexpr (__is_same(OutT, float))
          C[(size_t)row * N + col] = v;
        else
          C[(size_t)row * N + col] = (bf16_t)v;
      }
}

// ---------------- RoPE: qkv[4096][3072] -> Qr, Kr (coalesced only) --------
__global__ __launch_bounds__(256) void rope_layout(
    const bf16_t* __restrict__ qkv, const float* __restrict__ fc,
    const float* __restrict__ fs, bf16_t* __restrict__ Qr,
    bf16_t* __restrict__ Kr) {
  const int n = blockIdx.x;
  const int b = n >> 11, t = n & 2047;
  const int tid = threadIdx.x;
  const bf16_t* row = qkv + (size_t)n * 3072;

#pragma unroll
  for (int i = 0; i < 4; ++i) {
    const int p = i * 256 + tid;
    const int h = p >> 6, j = p & 63;
    const float t0 = (float)row[h * 128 + 2 * j];
    const float t1 = (float)row[h * 128 + 2 * j + 1];
    const float c = fc[t * 64 + j], s = fs[t * 64 + j];
    const size_t dst = ((size_t)(b * 16 + h) * 2048 + t) * 128 + 2 * j;
    Qr[dst] = (bf16_t)((t0 * c - t1 * s) * SCALE_Q2);
    Qr[dst + 1] = (bf16_t)((t0 * s + t1 * c) * SCALE_Q2);
  }
  {
    const int kvh = tid >> 6, j = tid & 63;
    const float t0 = (float)row[2048 + kvh * 128 + 2 * j];
    const float t1 = (float)row[2048 + kvh * 128 + 2 * j + 1];
    const float c = fc[t * 64 + j], s = fs[t * 64 + j];
    const size_t dst = ((size_t)(b * 4 + kvh) * 2048 + t) * 128 + 2 * j;
    Kr[dst] = (bf16_t)(t0 * c - t1 * s);
    Kr[dst + 1] = (bf16_t)(t0 * s + t1 * c);
  }
}

// ---------------- V transpose: qkv -> Vt[B*4][128][2048], LDS-tiled --------
// Token columns permuted within 16-groups (swap bits 2<->3 of t&15).
__global__ __launch_bounds__(256) void v_trans(
    const bf16_t* __restrict__ qkv, bf16_t* __restrict__ Vt) {
  __shared__ bf16_t L[64][68];
  const int bid = blockIdx.x;
  const int tt = bid & 31;
  const int dt2 = (bid >> 5) & 1;
  const int bk = bid >> 6;
  const int b = bk >> 2, kvh = bk & 3;
  const int t0 = tt * 64, d0 = dt2 * 64;
  const int r = threadIdx.x >> 4;
  const int c4 = (threadIdx.x & 15) * 4;

#pragma unroll
  for (int it = 0; it < 4; ++it) {
    const int tl = r + it * 16;
    const int tp = (tl & ~15) |
                   ((tl & 3) | ((tl & 4) << 1) | ((tl & 8) >> 1));
    const bf16_t* src = qkv + (size_t)(b * 2048 + t0 + tl) * 3072 + 2560 +
                        kvh * 128 + d0 + c4;
    *reinterpret_cast<bf16x4*>(&L[tp][c4]) =
        *reinterpret_cast<const bf16x4*>(src);
  }
  __syncthreads();
#pragma unroll
  for (int it = 0; it < 4; ++it) {
    const int dr = r + it * 16;
    bf16x4 v;
#pragma unroll
    for (int j = 0; j < 4; ++j) v[j] = L[c4 + j][dr];
    *reinterpret_cast<bf16x4*>(Vt + ((size_t)bk * 128 + d0 + dr) * 2048 +
                               t0 + c4) = v;
  }
}

// ---------------- causal GQA flash attention (32x32 MFMA, swapped QK) ------
// Round-10 exact structure (best known: 84.5us): 4 waves x 32q, KVBLK=128,
// K dbuf 64KB, kf-pair QK^T + V ping-pong register prefetch AFTER barrier
// (round 14's pre-barrier hoist cost +6us: live ranges across barrier).
#define VLOAD(buf, kf, kc)                                               \
  {                                                                      \
    _Pragma("unroll") for (int dtile_ = 0; dtile_ < 4; ++dtile_)         \
        buf[dtile_] = *reinterpret_cast<const bf16x8*>(                  \
            Vbase + (size_t)(dtile_ * 32 + l31) * 2048 + k0 + (kf) * 32 +\
            (kc) * 16 + hi * 8);                                         \
  }

__global__ __launch_bounds__(256, 2) void attn_fwd(
    const bf16_t* __restrict__ Qr, const bf16_t* __restrict__ Kr,
    const bf16_t* __restrict__ Vt, bf16_t* __restrict__ Oout) {
  __shared__ __align__(16) bf16_t Klds[2][128 * 128];
  const int tid = threadIdx.x;
  const int lane = tid & 63, w = tid >> 6;
  const int l31 = lane & 31, hi = lane >> 5;
  const int sidx = blockIdx.x >> 5;
  const int hb = blockIdx.x & 31;
  const int h = hb & 15, b = hb >> 4;
  const int kvh = h >> 2;
  const int st = (sidx < 8) ? (15 - sidx) : (sidx - 8);

  const bf16_t* Kbase = Kr + ((size_t)(b * 4 + kvh) * 2048) * 128;
  const bf16_t* Vbase = Vt + ((size_t)(b * 4 + kvh) * 128) * 2048;

  const int qbw = st * 128 + w * 32;
  const bf16_t* Qbase = Qr + ((size_t)(b * 16 + h) * 2048 + qbw + l31) * 128;

  auto STAGE = [&](bf16_t* dst, int kt) {
    const int k0s = kt * 128;
#pragma unroll
    for (int i = 0; i < 8; ++i) {
      const int c = i * 256 + tid;
      const int row = c >> 4;
      const int col = c & 15;
      const int scol = col ^ (row & 15);
      gload_lds16(Kbase + (size_t)(k0s + row) * 128 + scol * 8, dst + c * 8);
    }
  };

  STAGE(&Klds[0][0], 0);

  bf16x8 qf[8];
#pragma unroll
  for (int dt = 0; dt < 8; ++dt)
    qf[dt] = *reinterpret_cast<const bf16x8*>(Qbase + dt * 16 + hi * 8);

  f32x16 o[4];
#pragma unroll
  for (int d = 0; d < 4; ++d)
#pragma unroll
    for (int r = 0; r < 16; ++r) o[d][r] = 0.f;
  float lsum = 0.f;

  const int nt = st + 1;
  int cur = 0;
  for (int kt = 0; kt < nt; ++kt) {
    const int k0 = kt * 128;
    const bool last = (kt == nt - 1);
    const int kfmax = last ? w : 3;

    __syncthreads();  // prev STAGE drained; all readers of other buf done
    if (kt + 1 < nt) STAGE(&Klds[cur ^ 1][0], kt + 1);

    const char* KB = (const char*)&Klds[cur][0];

    // prologue V prefetch for kf=0 (lands under QK pair 0)
    bf16x8 vaA[4], vaB[4];
    VLOAD(vaA, 0, 0);
    VLOAD(vaB, 0, 1);

#pragma unroll
    for (int kp = 0; kp < 2; ++kp) {
      // ---- QK^T for kf pair (2kp, 2kp+1): two independent MFMA chains ----
      f32x16 sA, sB;
      __builtin_amdgcn_s_setprio(1);
      if (2 * kp <= kfmax) {
#pragma unroll
        for (int r = 0; r < 16; ++r) sA[r] = 0.f;
#pragma unroll
        for (int dt = 0; dt < 8; ++dt) {
          const int boff = ((2 * kp) * 32 + l31) * 256 +
                           ((dt * 32 + hi * 16) ^ ((l31 & 15) << 4));
          bf16x8 ka = *reinterpret_cast<const bf16x8*>(KB + boff);
          sA = __builtin_amdgcn_mfma_f32_32x32x16_bf16(ka, qf[dt], sA, 0, 0, 0);
        }
      }
      if (2 * kp + 1 <= kfmax) {
#pragma unroll
        for (int r = 0; r < 16; ++r) sB[r] = 0.f;
#pragma unroll
        for (int dt = 0; dt < 8; ++dt) {
          const int boff = ((2 * kp + 1) * 32 + l31) * 256 +
                           ((dt * 32 + hi * 16) ^ ((l31 & 15) << 4));
          bf16x8 ka = *reinterpret_cast<const bf16x8*>(KB + boff);
          sB = __builtin_amdgcn_mfma_f32_32x32x16_bf16(ka, qf[dt], sB, 0, 0, 0);
        }
      }
      __builtin_amdgcn_s_setprio(0);

      // ---- softmax + PV per kf in the pair ----
#pragma unroll
      for (int ki = 0; ki < 2; ++ki) {
        const int kf = 2 * kp + ki;
        if (kf <= kfmax) {
          const bool diag = last && (kf == w);
          float p[16];
#pragma unroll
          for (int r = 0; r < 16; ++r) {
            float e = exp2f(ki ? sB[r] : sA[r]);
            if (diag) {
              const int crow = (r & 3) + 8 * (r >> 2) + 4 * hi;
              if (crow > l31) e = 0.f;
            }
            p[r] = e;
          }
          const float t0 = (p[0] + p[1]) + (p[2] + p[3]);
          const float t1 = (p[4] + p[5]) + (p[6] + p[7]);
          const float t2 = (p[8] + p[9]) + (p[10] + p[11]);
          const float t3 = (p[12] + p[13]) + (p[14] + p[15]);
          lsum += (t0 + t1) + (t2 + t3);

          // kc0: consume vaA, then reload it for kf+1
          {
            unsigned int u0, u1, u2, u3;
            asm("v_cvt_pk_bf16_f32 %0, %1, %2" : "=v"(u0)
                : "v"(p[0]), "v"(p[1]));
            asm("v_cvt_pk_bf16_f32 %0, %1, %2" : "=v"(u1)
                : "v"(p[2]), "v"(p[3]));
            asm("v_cvt_pk_bf16_f32 %0, %1, %2" : "=v"(u2)
                : "v"(p[4]), "v"(p[5]));
            asm("v_cvt_pk_bf16_f32 %0, %1, %2" : "=v"(u3)
                : "v"(p[6]), "v"(p[7]));
            union { unsigned int u[4]; bf16x8 v; } pb;
            pb.u[0] = u0; pb.u[1] = u1; pb.u[2] = u2; pb.u[3] = u3;
            __builtin_amdgcn_s_setprio(1);
#pragma unroll
            for (int dtile = 0; dtile < 4; ++dtile)
              o[dtile] = __builtin_amdgcn_mfma_f32_32x32x16_bf16(
                  vaA[dtile], pb.v, o[dtile], 0, 0, 0);
            __builtin_amdgcn_s_setprio(0);
          }
          if (kf < kfmax) VLOAD(vaA, kf + 1, 0);

          // kc1: consume vaB, then reload it for kf+1
          {
            unsigned int u0, u1, u2, u3;
            asm("v_cvt_pk_bf16_f32 %0, %1, %2" : "=v"(u0)
                : "v"(p[8]), "v"(p[9]));
            asm("v_cvt_pk_bf16_f32 %0, %1, %2" : "=v"(u1)
                : "v"(p[10]), "v"(p[11]));
            asm("v_cvt_pk_bf16_f32 %0, %1, %2" : "=v"(u2)
                : "v"(p[12]), "v"(p[13]));
            asm("v_cvt_pk_bf16_f32 %0, %1, %2" : "=v"(u3)
                : "v"(p[14]), "v"(p[15]));
            union { unsigned int u[4]; bf16x8 v; } pb;
            pb.u[0] = u0; pb.u[1] = u1; pb.u[2] = u2; pb.u[3] = u3;
            __builtin_amdgcn_s_setprio(1);
#pragma unroll
            for (int dtile = 0; dtile < 4; ++dtile)
              o[dtile] = __builtin_amdgcn_mfma_f32_32x32x16_bf16(
                  vaB[dtile], pb.v, o[dtile], 0, 0, 0);
            __builtin_amdgcn_s_setprio(0);
          }
          if (kf < kfmax) VLOAD(vaB, kf + 1, 1);
        }
      }
    }
    cur ^= 1;
  }

  // ---- epilogue: normalize + store O^T (col=q, row=d) ----
  const float ltot = lsum + __shfl_xor(lsum, 32);
  const float inv = 1.f / ltot;
  bf16_t* Obase = Oout + ((size_t)b * 2048 + qbw + l31) * 2048 + h * 128;
#pragma unroll
  for (int dtile = 0; dtile < 4; ++dtile)
#pragma unroll
    for (int g = 0; g < 4; ++g) {
      bf16x4 stv;
#pragma unroll
      for (int j = 0; j < 4; ++j)
        stv[j] = (bf16_t)(o[dtile][g * 4 + j] * inv);
      *reinterpret_cast<bf16x4*>(Obase + dtile * 32 + 8 * g + 4 * hi) = stv;
    }
}

// ---------------- host launch ----------------
extern "C" void kernel_launch(void* const* d_in, const int* in_sizes, int n_in,
                              void* d_out, int out_size, void* d_ws,
                              size_t ws_size, hipStream_t stream) {
  const float* x  = (const float*)d_in[0];
  const float* wq = (const float*)d_in[1];
  const float* wk = (const float*)d_in[2];
  const float* wv = (const float*)d_in[3];
  const float* wo = (const float*)d_in[4];
  const float* fc = (const float*)d_in[5];
  const float* fs = (const float*)d_in[6];
  float* out = (float*)d_out;

  char* ws = (char*)d_ws;
  bf16_t* xb      = (bf16_t*)(ws + 0);
  bf16_t* wqkv    = (bf16_t*)(ws + 16777216);
  bf16_t* wo_b    = (bf16_t*)(ws + 29360128);
  bf16_t* qkv     = (bf16_t*)(ws + 37748736);
  bf16_t* Qr      = (bf16_t*)(ws + 62914560);
  bf16_t* Kr      = (bf16_t*)(ws + 79691776);
  bf16_t* Vt      = (bf16_t*)(ws + 83886080);
  bf16_t* attn_o  = xb;

  const int M = 4096;

  cvt_all<<<2048, 256, 0, stream>>>(x, wq, wk, wv, wo, xb, wqkv, wo_b);

  gemm_bt<bf16_t><<<dim3(3072 / 128, M / 128), 256, 0, stream>>>(
      xb, wqkv, qkv, M, 3072, 2048);

  rope_layout<<<4096, 256, 0, stream>>>(qkv, fc, fs, Qr, Kr);
  v_trans<<<512, 256, 0, stream>>>(qkv, Vt);

  attn_fwd<<<512, 256, 0, stream>>>(Qr, Kr, Vt, attn_o);

  gemm_bt<float><<<dim3(2048 / 128, M / 128), 256, 0, stream>>>(
      attn_o, wo_b, out, M, 2048, 2048);
}